// Round 1
// baseline (168.983 us; speedup 1.0000x reference)
//
#include <hip/hip_runtime.h>

// Ordered bi-bi mechanism dydt. Species: [E, EA, EQ, EAB, A, B, P, Q].
// Per element: 64 B in, 32 B out, ~12 flops -> pure HBM-bound streaming.

__global__ __launch_bounds__(256) void ode_kernel(
    const float* __restrict__ y,
    const float* __restrict__ kf,
    const float* __restrict__ kr,
    float* __restrict__ out,
    int B)
{
    int i = blockIdx.x * blockDim.x + threadIdx.x;
    if (i >= B) return;

    const float4* y4 = reinterpret_cast<const float4*>(y) + (size_t)i * 2;
    float4 ya = y4[0];                                   // E, EA, EQ, EAB
    float4 yb = y4[1];                                   // A, B, P, Q
    float4 f  = reinterpret_cast<const float4*>(kf)[i];  // kf0..kf3
    float4 r  = reinterpret_cast<const float4*>(kr)[i];  // kr0..kr3

    float E   = ya.x, EA = ya.y, EQ = ya.z, EAB = ya.w;
    float A   = yb.x, Bc = yb.y, P  = yb.z, Q   = yb.w;

    float v0 = f.x * E   * A  - r.x * EA;
    float v1 = f.y * EA  * Bc - r.y * EAB;
    float v2 = f.z * EAB      - r.z * EQ * P;
    float v3 = f.w * EQ       - r.w * E  * Q;

    float4 o0, o1;
    o0.x = v3 - v0;   // dE
    o0.y = v0 - v1;   // dEA
    o0.z = v2 - v3;   // dEQ
    o0.w = v1 - v2;   // dEAB
    o1.x = -v0;       // dA
    o1.y = -v1;       // dB
    o1.z =  v2;       // dP
    o1.w =  v3;       // dQ

    float4* out4 = reinterpret_cast<float4*>(out) + (size_t)i * 2;
    out4[0] = o0;
    out4[1] = o1;
}

extern "C" void kernel_launch(void* const* d_in, const int* in_sizes, int n_in,
                              void* d_out, int out_size, void* d_ws, size_t ws_size,
                              hipStream_t stream) {
    // inputs: [0]=t (1,), [1]=y (B,8), [2]=forward_rates (B,4), [3]=reverse_rates (B,4)
    const float* y  = (const float*)d_in[1];
    const float* kf = (const float*)d_in[2];
    const float* kr = (const float*)d_in[3];
    float* out = (float*)d_out;
    int B = in_sizes[1] / 8;

    int block = 256;
    int grid = (B + block - 1) / block;
    ode_kernel<<<grid, block, 0, stream>>>(y, kf, kr, out, B);
}

// Round 2
// 168.192 us; speedup vs baseline: 1.0047x; 1.0047x over previous
//
#include <hip/hip_runtime.h>

// Ordered bi-bi mechanism dydt. Species: [E, EA, EQ, EAB, A, B, P, Q].
// Two lanes per element: lane pair (2j, 2j+1) holds the two float4 halves of
// element j's y-row, so every global load/store is unit-stride float4 across
// the wave (minimal cache-line touches). Halves + rates exchanged via
// __shfl_xor(.,1); both lanes redundantly compute the 4 net rates.

__global__ __launch_bounds__(256) void ode_kernel(
    const float4* __restrict__ y4,
    const float4* __restrict__ kf4,
    const float4* __restrict__ kr4,
    float4* __restrict__ out4,
    int n2)   // n2 = 2*B (total float4 rows of y)
{
    int t = blockIdx.x * blockDim.x + threadIdx.x;
    if (t >= n2) return;

    int e = t >> 1;   // element index
    int h = t & 1;    // which half this lane loaded

    float4 q = y4[t];  // unit-stride float4 load

    // neighbor-lane exchange: get the other half of this element
    float4 p;
    p.x = __shfl_xor(q.x, 1);
    p.y = __shfl_xor(q.y, 1);
    p.z = __shfl_xor(q.z, 1);
    p.w = __shfl_xor(q.w, 1);

    float4 ya = h ? p : q;   // E, EA, EQ, EAB
    float4 yb = h ? q : p;   // A, B, P, Q

    // even lane fetches forward rates, odd lane reverse rates; then exchange
    const float4* __restrict__ rp = h ? kr4 : kf4;
    float4 mine = rp[e];
    float4 other;
    other.x = __shfl_xor(mine.x, 1);
    other.y = __shfl_xor(mine.y, 1);
    other.z = __shfl_xor(mine.z, 1);
    other.w = __shfl_xor(mine.w, 1);

    float4 f = h ? other : mine;   // kf0..kf3
    float4 r = h ? mine : other;   // kr0..kr3

    float E  = ya.x, EA = ya.y, EQ = ya.z, EAB = ya.w;
    float A  = yb.x, Bc = yb.y, P  = yb.z, Q   = yb.w;

    float v0 = f.x * E   * A  - r.x * EA;
    float v1 = f.y * EA  * Bc - r.y * EAB;
    float v2 = f.z * EAB      - r.z * EQ * P;
    float v3 = f.w * EQ       - r.w * E  * Q;

    float4 o;
    if (h == 0) {
        o.x = v3 - v0;   // dE
        o.y = v0 - v1;   // dEA
        o.z = v2 - v3;   // dEQ
        o.w = v1 - v2;   // dEAB
    } else {
        o.x = -v0;       // dA
        o.y = -v1;       // dB
        o.z =  v2;       // dP
        o.w =  v3;       // dQ
    }

    out4[t] = o;  // unit-stride float4 store
}

extern "C" void kernel_launch(void* const* d_in, const int* in_sizes, int n_in,
                              void* d_out, int out_size, void* d_ws, size_t ws_size,
                              hipStream_t stream) {
    // inputs: [0]=t (1,), [1]=y (B,8), [2]=forward_rates (B,4), [3]=reverse_rates (B,4)
    const float4* y4  = (const float4*)d_in[1];
    const float4* kf4 = (const float4*)d_in[2];
    const float4* kr4 = (const float4*)d_in[3];
    float4* out4 = (float4*)d_out;
    int B  = in_sizes[1] / 8;
    int n2 = 2 * B;

    int block = 256;
    int grid = (n2 + block - 1) / block;
    ode_kernel<<<grid, block, 0, stream>>>(y4, kf4, kr4, out4, n2);
}